// Round 16
// baseline (236.569 us; speedup 1.0000x reference)
//
#include <hip/hip_runtime.h>
#include <hip/hip_bf16.h>

typedef __bf16 bf16x8 __attribute__((ext_vector_type(8)));
typedef float f32x4 __attribute__((ext_vector_type(4)));
typedef float f32x2 __attribute__((ext_vector_type(2)));

#define MT 128  // tokens per block
#define CC 256

// swizzled LDS byte offset, [.][256] bf16 tile (row stride 512B)
__device__ __forceinline__ int swz(int r, int c) {
    return r * 512 + ((c * 2) ^ ((r & 7) << 4));
}

// packed-B fragment load: tile (nc, kc) of 16 cols x 32 k, 1KB contiguous
__device__ __forceinline__ bf16x8 ldB(const __bf16* __restrict__ WT, int nc, int KC, int kc,
                                      int laneoff) {
    return *(const bf16x8*)(WT + ((size_t)nc * KC + kc) * 512 + laneoff);
}

// issue-early staging: NT-load 128x256 fp32 tile, convert to bf16, hold packed (32 VGPR)
__device__ __forceinline__ void stage_issue(const float* __restrict__ src, int row0, int tid,
                                            unsigned long long (&h)[16]) {
#pragma unroll
    for (int i = 0; i < 16; ++i) {
        int f = i * 512 + tid;
        int r = f >> 6;
        int c = (f & 63) * 4;
        f32x4 v = __builtin_nontemporal_load((const f32x4*)(src + (size_t)(row0 + r) * CC + c));
        union { __bf16 b[4]; unsigned long long u; } uu;
        uu.b[0] = (__bf16)v[0]; uu.b[1] = (__bf16)v[1];
        uu.b[2] = (__bf16)v[2]; uu.b[3] = (__bf16)v[3];
        h[i] = uu.u;
    }
}
__device__ __forceinline__ void stage_retire(__bf16* dst, int tid,
                                             const unsigned long long (&h)[16]) {
#pragma unroll
    for (int i = 0; i < 16; ++i) {
        int f = i * 512 + tid;
        int r = f >> 6;
        int c = (f & 63) * 4;
        *(unsigned long long*)((char*)dst + swz(r, c)) = h[i];
    }
}

// weight prep: transpose + bf16 + FRAGMENT-PACK (16col x 32k tiles = 1KB contiguous,
// element order lane*8+e). layout (bf16 elem offsets):
//   WTqp @0 (K=512,N=256: k<256 Wq else Wpos) | WTkp @131072 (Wk/Wpos)
//   WTo1 @262144 (K=256,N=512) | WTo2 @393216 (K=512,N=64)
//   WTv @425984 (K=256,N=256) | WTout @491520 (K=256,N=256)
__global__ void prep_all(const float* __restrict__ Wq, const float* __restrict__ Wk,
                         const float* __restrict__ Wpos, const float* __restrict__ Wo1,
                         const float* __restrict__ Wo2, const float* __restrict__ Wv,
                         const float* __restrict__ Wout, __bf16* __restrict__ ws)
{
    int i = blockIdx.x * 256 + threadIdx.x;
    if (i >= 557056) return;
    int j, K, N;
    const float* S0 = nullptr; const float* S1 = nullptr;
    if (i < 131072)      { j = i;          K = 512; N = 256; S0 = Wq;  S1 = Wpos; }
    else if (i < 262144) { j = i - 131072; K = 512; N = 256; S0 = Wk;  S1 = Wpos; }
    else if (i < 393216) { j = i - 262144; K = 256; N = 512; S0 = Wo1; }
    else if (i < 425984) { j = i - 393216; K = 512; N = 64;  S0 = Wo2; }
    else if (i < 491520) { j = i - 425984; K = 256; N = 256; S0 = Wv; }
    else                 { j = i - 491520; K = 256; N = 256; S0 = Wout; }
    int tile = j >> 9, r = j & 511;
    int lane = r >> 3, e = r & 7;
    int q4 = lane >> 4, r16 = lane & 15;
    int KC = K >> 5;
    int nc = tile / KC, kc = tile - nc * KC;
    int k = kc * 32 + q4 * 8 + e;
    int n = nc * 16 + r16;
    float v;
    if (S1 && k >= 256) v = S1[(size_t)(k - 256) * N + n];
    else                v = S0[(size_t)k * N + n];
    ws[i] = (__bf16)v;
}

// ============ fused kernel: MT=128, 512 threads (8 waves), 152KB LDS, 1 block/CU ============
// NOTE: 1024-thread workgroups get a hard 64-VGPR cap on this toolchain (r12/r14/r15) ->
// stay at 512 threads; (512,1) allows up to 256 VGPR (2 waves/SIMD), LDS forces 1 block/CU.
extern "C" __global__ void __launch_bounds__(512, 1)
fused_ext_attn(const float* __restrict__ query, const float* __restrict__ key,
               const float* __restrict__ value, const float* __restrict__ refp,
               const float* __restrict__ pose,
               const __bf16* __restrict__ ws,
               const float* __restrict__ bq, const float* __restrict__ bk,
               const float* __restrict__ bv, const float* __restrict__ bpos,
               const float* __restrict__ bo1, const float* __restrict__ bo2,
               const float* __restrict__ bout,
               float* __restrict__ out)
{
    const __bf16* WTqp  = ws;             // KC=16
    const __bf16* WTkp  = ws + 131072;    // KC=16
    const __bf16* WTo1  = ws + 262144;    // KC=8
    const __bf16* WTo2  = ws + 393216;    // KC=16
    const __bf16* WTv   = ws + 425984;    // KC=8
    const __bf16* WTout = ws + 491520;    // KC=8

    __shared__ __attribute__((aligned(16))) __bf16 SA[MT * CC];   // query -> key -> value
    __shared__ __attribute__((aligned(16))) __bf16 SB[MT * CC];   // h1 -> pose -> o
    __shared__ __attribute__((aligned(16))) char   SY[24576];     // off_b / qk / wv

    __bf16* off_b = (__bf16*)SY;            // [128][64] bf16
    float*  qk_s  = (float*)(SY + 16384);   // [128][8]
    float*  wv_s  = (float*)(SY + 20480);   // [128][8]

    const int tid = threadIdx.x;
    const int lane = tid & 63;
    const int wid = tid >> 6;        // 0..7 — wave owns 32 cols (= 1 head) in N=256 phases
    const int r16 = lane & 15;
    const int q4 = lane >> 4;
    const int laneoff = lane * 8;
    const int row0 = blockIdx.x * MT;

    // ---- S1: stream query -> SA ----
    {
        unsigned long long hq[16];
        stage_issue(query, row0, tid, hq);
        stage_retire(SA, tid, hq);
    }
    __syncthreads();                                   // B1

    // ---- S2..S5: h1 (2x256-col passes into SB) + off partials; pose issued under S2 ----
    unsigned long long hpose[16];
    stage_issue(pose, row0, tid, hpose);
    f32x4 accO[4];
#pragma unroll
    for (int i = 0; i < 4; ++i) accO[i] = (f32x4){0.f, 0.f, 0.f, 0.f};
    for (int p = 0; p < 2; ++p) {
        f32x4 acc[8][2];
#pragma unroll
        for (int i = 0; i < 8; ++i)
#pragma unroll
            for (int j = 0; j < 2; ++j) acc[i][j] = (f32x4){0.f, 0.f, 0.f, 0.f};
#pragma unroll
        for (int ks = 0; ks < 8; ++ks) {
            int ak = ks * 32 + q4 * 8;
            bf16x8 a[8], b[2];
#pragma unroll
            for (int mf = 0; mf < 8; ++mf)
                a[mf] = *(const bf16x8*)((const char*)SA + swz(mf * 16 + r16, ak));
#pragma unroll
            for (int nf = 0; nf < 2; ++nf)
                b[nf] = ldB(WTo1, p * 16 + wid * 2 + nf, 8, ks, laneoff);
#pragma unroll
            for (int mf = 0; mf < 8; ++mf)
#pragma unroll
                for (int nf = 0; nf < 2; ++nf)
                    acc[mf][nf] = __builtin_amdgcn_mfma_f32_16x16x32_bf16(a[mf], b[nf], acc[mf][nf], 0, 0, 0);
        }
#pragma unroll
        for (int mf = 0; mf < 8; ++mf)
#pragma unroll
            for (int nf = 0; nf < 2; ++nf) {
                int lcol = wid * 32 + nf * 16 + r16;
                float bias = bo1[p * 256 + lcol];
#pragma unroll
                for (int r = 0; r < 4; ++r)
                    *(__bf16*)((char*)SB + swz(mf * 16 + q4 * 4 + r, lcol)) =
                        (__bf16)fmaxf(acc[mf][nf][r] + bias, 0.f);
            }
        __syncthreads();                               // h1 pass ready
        // off partial: wave (wid&3) owns 16 off-cols, (wid>>2) selects 64-row half
        {
            int rbase = (wid >> 2) * 64;
#pragma unroll
            for (int ks = 0; ks < 8; ++ks) {
                int ak = ks * 32 + q4 * 8;
                bf16x8 b = ldB(WTo2, wid & 3, 16, p * 8 + ks, laneoff);
#pragma unroll
                for (int mf = 0; mf < 4; ++mf) {
                    bf16x8 a = *(const bf16x8*)((const char*)SB + swz(rbase + mf * 16 + r16, ak));
                    accO[mf] = __builtin_amdgcn_mfma_f32_16x16x32_bf16(a, b, accO[mf], 0, 0, 0);
                }
            }
            if (p == 1) {
                int col = (wid & 3) * 16 + r16;
                float b2 = bo2[col];
#pragma unroll
                for (int mf = 0; mf < 4; ++mf)
#pragma unroll
                    for (int r = 0; r < 4; ++r)
                        off_b[(rbase + mf * 16 + q4 * 4 + r) * 64 + col] = (__bf16)(accO[mf][r] + b2);
            }
        }
        __syncthreads();                               // SB reads done / dead
    }

    // ---- S6: retire pose -> SB ----
    stage_retire(SB, tid, hpose);
    __syncthreads();                                   // B6

    // ---- S7: q-GEMM K=512 (query in SA, pose in SB) -> qa regs; issue key loads ----
    unsigned long long hkey[16];
    stage_issue(key, row0, tid, hkey);
    f32x4 qa[8][2];
#pragma unroll
    for (int i = 0; i < 8; ++i)
#pragma unroll
        for (int j = 0; j < 2; ++j) qa[i][j] = (f32x4){0.f, 0.f, 0.f, 0.f};
#pragma unroll
    for (int ks = 0; ks < 16; ++ks) {
        int ak = (ks & 7) * 32 + q4 * 8;
        const char* Abase = (ks < 8) ? (const char*)SA : (const char*)SB;
        bf16x8 a[8], b[2];
#pragma unroll
        for (int mf = 0; mf < 8; ++mf)
            a[mf] = *(const bf16x8*)(Abase + swz(mf * 16 + r16, ak));
#pragma unroll
        for (int nf = 0; nf < 2; ++nf)
            b[nf] = ldB(WTqp, wid * 2 + nf, 16, ks, laneoff);
#pragma unroll
        for (int mf = 0; mf < 8; ++mf)
#pragma unroll
            for (int nf = 0; nf < 2; ++nf)
                qa[mf][nf] = __builtin_amdgcn_mfma_f32_16x16x32_bf16(a[mf], b[nf], qa[mf][nf], 0, 0, 0);
    }
    __syncthreads();                                   // B7 (SA reads done)

    // ---- S8: retire key -> SA ----
    stage_retire(SA, tid, hkey);
    __syncthreads();                                   // B8

    // ---- S9: k-GEMM K=512 (key in SA, pose in SB) + head dot -> qk_s; issue value ----
    unsigned long long hval[16];
    stage_issue(value, row0, tid, hval);
    {
        f32x4 ka[8][2];
#pragma unroll
        for (int i = 0; i < 8; ++i)
#pragma unroll
            for (int j = 0; j < 2; ++j) ka[i][j] = (f32x4){0.f, 0.f, 0.f, 0.f};
#pragma unroll
        for (int ks = 0; ks < 16; ++ks) {
            int ak = (ks & 7) * 32 + q4 * 8;
            const char* Abase = (ks < 8) ? (const char*)SA : (const char*)SB;
            bf16x8 a[8], b[2];
#pragma unroll
            for (int mf = 0; mf < 8; ++mf)
                a[mf] = *(const bf16x8*)(Abase + swz(mf * 16 + r16, ak));
#pragma unroll
            for (int nf = 0; nf < 2; ++nf)
                b[nf] = ldB(WTkp, wid * 2 + nf, 16, ks, laneoff);
#pragma unroll
            for (int mf = 0; mf < 8; ++mf)
#pragma unroll
                for (int nf = 0; nf < 2; ++nf)
                    ka[mf][nf] = __builtin_amdgcn_mfma_f32_16x16x32_bf16(a[mf], b[nf], ka[mf][nf], 0, 0, 0);
        }
        float Bq[2], Bk[2];
#pragma unroll
        for (int nf = 0; nf < 2; ++nf) {
            int col = wid * 32 + nf * 16 + r16;
            Bq[nf] = bq[col] + bpos[col];
            Bk[nf] = bk[col] + bpos[col];
        }
#pragma unroll
        for (int mf = 0; mf < 8; ++mf)
#pragma unroll
            for (int r = 0; r < 4; ++r) {
                float p = (qa[mf][0][r] + Bq[0]) * (ka[mf][0][r] + Bk[0])
                        + (qa[mf][1][r] + Bq[1]) * (ka[mf][1][r] + Bk[1]);
#pragma unroll
                for (int m = 1; m < 16; m <<= 1)
                    p += __shfl_xor(p, m);
                if (r16 == 0)
                    qk_s[(mf * 16 + q4 * 4 + r) * 8 + wid] = p;
            }
    }
    __syncthreads();                                   // B9

    // ---- S10: retire value -> SA; softmax (1024 jobs, 2/thread) -> wv_s ----
    stage_retire(SA, tid, hval);
#pragma unroll
    for (int pi = 0; pi < 2; ++pi) {
        int idx = tid + pi * 512;
        int t = idx >> 3, h = idx & 7;
        float qk = qk_s[t * 8 + h];
        f32x2 rp = __builtin_nontemporal_load((const f32x2*)(refp + (size_t)(row0 + t) * 2));
        float wgt[4], lg[4];
        float m = -1e30f;
#pragma unroll
        for (int kk = 0; kk < 4; ++kk) {
            float ox = (float)off_b[t * 64 + (h * 4 + kk) * 2];
            float oy = (float)off_b[t * 64 + (h * 4 + kk) * 2 + 1];
            float cx = rp[0] + ox - 0.5f, cy = rp[1] + oy - 0.5f;
            float wx = fmaxf(0.f, 1.f - fabsf(cx));
            float wy = fmaxf(0.f, 1.f - fabsf(cy));
            wgt[kk] = wx * wy;
            lg[kk] = qk * wgt[kk] * 0.17677669529663687f;  // 1/sqrt(32)
            m = fmaxf(m, lg[kk]);
        }
        float s = 0.f, sw = 0.f;
#pragma unroll
        for (int kk = 0; kk < 4; ++kk) {
            float e = __expf(lg[kk] - m);
            s += e;
            sw += e * wgt[kk];
        }
        wv_s[t * 8 + h] = sw / s;
    }
    __syncthreads();                                   // B10

    // ---- S11: o = (value@Wv + bv) * wv -> SB (pose dead) ----
    {
        f32x4 acc[8][2];
#pragma unroll
        for (int i = 0; i < 8; ++i)
#pragma unroll
            for (int j = 0; j < 2; ++j) acc[i][j] = (f32x4){0.f, 0.f, 0.f, 0.f};
#pragma unroll
        for (int ks = 0; ks < 8; ++ks) {
            int ak = ks * 32 + q4 * 8;
            bf16x8 a[8], b[2];
#pragma unroll
            for (int mf = 0; mf < 8; ++mf)
                a[mf] = *(const bf16x8*)((const char*)SA + swz(mf * 16 + r16, ak));
#pragma unroll
            for (int nf = 0; nf < 2; ++nf)
                b[nf] = ldB(WTv, wid * 2 + nf, 8, ks, laneoff);
#pragma unroll
            for (int mf = 0; mf < 8; ++mf)
#pragma unroll
                for (int nf = 0; nf < 2; ++nf)
                    acc[mf][nf] = __builtin_amdgcn_mfma_f32_16x16x32_bf16(a[mf], b[nf], acc[mf][nf], 0, 0, 0);
        }
#pragma unroll
        for (int mf = 0; mf < 8; ++mf)
#pragma unroll
            for (int nf = 0; nf < 2; ++nf) {
                int col = wid * 32 + nf * 16 + r16;   // head = wid
                float bias = bv[col];
#pragma unroll
                for (int r = 0; r < 4; ++r) {
                    int row = mf * 16 + q4 * 4 + r;
                    float wvv = wv_s[row * 8 + wid];
                    *(__bf16*)((char*)SB + swz(row, col)) = (__bf16)((acc[mf][nf][r] + bias) * wvv);
                }
            }
    }
    __syncthreads();                                   // B11

    // ---- S12: out = o @ WTout + bout -> global (NT store) ----
    {
        f32x4 acc[8][2];
#pragma unroll
        for (int i = 0; i < 8; ++i)
#pragma unroll
            for (int j = 0; j < 2; ++j) acc[i][j] = (f32x4){0.f, 0.f, 0.f, 0.f};
#pragma unroll
        for (int ks = 0; ks < 8; ++ks) {
            int ak = ks * 32 + q4 * 8;
            bf16x8 a[8], b[2];
#pragma unroll
            for (int mf = 0; mf < 8; ++mf)
                a[mf] = *(const bf16x8*)((const char*)SB + swz(mf * 16 + r16, ak));
#pragma unroll
            for (int nf = 0; nf < 2; ++nf)
                b[nf] = ldB(WTout, wid * 2 + nf, 8, ks, laneoff);
#pragma unroll
            for (int mf = 0; mf < 8; ++mf)
#pragma unroll
                for (int nf = 0; nf < 2; ++nf)
                    acc[mf][nf] = __builtin_amdgcn_mfma_f32_16x16x32_bf16(a[mf], b[nf], acc[mf][nf], 0, 0, 0);
        }
#pragma unroll
        for (int mf = 0; mf < 8; ++mf)
#pragma unroll
            for (int nf = 0; nf < 2; ++nf) {
                int col = wid * 32 + nf * 16 + r16;
                float bias = bout[col];
#pragma unroll
                for (int r = 0; r < 4; ++r) {
                    int row = mf * 16 + q4 * 4 + r;
                    __builtin_nontemporal_store(acc[mf][nf][r] + bias,
                                                out + (size_t)(row0 + row) * CC + col);
                }
            }
    }
}

extern "C" void kernel_launch(void* const* d_in, const int* in_sizes, int n_in,
                              void* d_out, int out_size, void* d_ws, size_t ws_size,
                              hipStream_t stream)
{
    const float* query = (const float*)d_in[0];
    const float* key   = (const float*)d_in[1];
    const float* value = (const float*)d_in[2];
    const float* refp  = (const float*)d_in[3];
    const float* pose  = (const float*)d_in[4];
    const float* Wq  = (const float*)d_in[5];  const float* bq   = (const float*)d_in[6];
    const float* Wk  = (const float*)d_in[7];  const float* bk   = (const float*)d_in[8];
    const float* Wv  = (const float*)d_in[9];  const float* bv   = (const float*)d_in[10];
    const float* Wo1 = (const float*)d_in[11]; const float* bo1  = (const float*)d_in[12];
    const float* Wo2 = (const float*)d_in[13]; const float* bo2  = (const float*)d_in[14];
    const float* Wpos= (const float*)d_in[15]; const float* bpos = (const float*)d_in[16];
    const float* Wout= (const float*)d_in[17]; const float* bout = (const float*)d_in[18];

    __bf16* ws = (__bf16*)d_ws;

    prep_all<<<2176, 256, 0, stream>>>(Wq, Wk, Wpos, Wo1, Wo2, Wv, Wout, ws);

    fused_ext_attn<<<65536 / MT, 512, 0, stream>>>(
        query, key, value, refp, pose, ws,
        bq, bk, bv, bpos, bo1, bo2, bout, (float*)d_out);
}

// Round 17
// 138.287 us; speedup vs baseline: 1.7107x; 1.7107x over previous
//
#include <hip/hip_runtime.h>
#include <hip/hip_bf16.h>

typedef __bf16 bf16x8 __attribute__((ext_vector_type(8)));
typedef float f32x4 __attribute__((ext_vector_type(4)));
typedef float f32x2 __attribute__((ext_vector_type(2)));

#define MT 64   // tokens per block
#define CC 256

// swizzled LDS byte offset, [.][256] bf16 tile (row stride 512B)
__device__ __forceinline__ int swz(int r, int c) {
    return r * 512 + ((c * 2) ^ ((r & 7) << 4));
}

// packed-B fragment load: tile (nc, kc) of 16 cols x 32 k, 1KB contiguous
__device__ __forceinline__ bf16x8 ldB(const __bf16* __restrict__ WT, int nc, int KC, int kc,
                                      int laneoff) {
    return *(const bf16x8*)(WT + ((size_t)nc * KC + kc) * 512 + laneoff);
}

// stream one 64x256 fp32 tile: NT load -> bf16 -> swizzled LDS write (8 iters/thread @512thr)
__device__ __forceinline__ void stream_tile(const float* __restrict__ src, int row0, int tid,
                                            __bf16* dst) {
#pragma unroll
    for (int i = 0; i < 8; ++i) {
        int f = i * 512 + tid;
        int r = f >> 6;
        int c = (f & 63) * 4;
        f32x4 v = __builtin_nontemporal_load((const f32x4*)(src + (size_t)(row0 + r) * CC + c));
        union { __bf16 h[4]; unsigned long long u; } uu;
        uu.h[0] = (__bf16)v[0]; uu.h[1] = (__bf16)v[1];
        uu.h[2] = (__bf16)v[2]; uu.h[3] = (__bf16)v[3];
        *(unsigned long long*)((char*)dst + swz(r, c)) = uu.u;
    }
}

// weight prep: transpose + bf16 + FRAGMENT-PACK (16col x 32k tiles = 1KB contiguous,
// element order lane*8+e). layout (bf16 elem offsets):
//   WTqp @0 (K=512,N=256: k<256 Wq else Wpos) | WTkp @131072 (Wk/Wpos)
//   WTo1 @262144 (K=256,N=512) | WTo2 @393216 (K=512,N=64)
//   WTv @425984 (K=256,N=256) | WTout @491520 (K=256,N=256)
__global__ void prep_all(const float* __restrict__ Wq, const float* __restrict__ Wk,
                         const float* __restrict__ Wpos, const float* __restrict__ Wo1,
                         const float* __restrict__ Wo2, const float* __restrict__ Wv,
                         const float* __restrict__ Wout, __bf16* __restrict__ ws)
{
    int i = blockIdx.x * 256 + threadIdx.x;
    if (i >= 557056) return;
    int j, K, N;
    const float* S0 = nullptr; const float* S1 = nullptr;
    if (i < 131072)      { j = i;          K = 512; N = 256; S0 = Wq;  S1 = Wpos; }
    else if (i < 262144) { j = i - 131072; K = 512; N = 256; S0 = Wk;  S1 = Wpos; }
    else if (i < 393216) { j = i - 262144; K = 256; N = 512; S0 = Wo1; }
    else if (i < 425984) { j = i - 393216; K = 512; N = 64;  S0 = Wo2; }
    else if (i < 491520) { j = i - 425984; K = 256; N = 256; S0 = Wv; }
    else                 { j = i - 491520; K = 256; N = 256; S0 = Wout; }
    int tile = j >> 9, r = j & 511;
    int lane = r >> 3, e = r & 7;
    int q4 = lane >> 4, r16 = lane & 15;
    int KC = K >> 5;
    int nc = tile / KC, kc = tile - nc * KC;
    int k = kc * 32 + q4 * 8 + e;
    int n = nc * 16 + r16;
    float v;
    if (S1 && k >= 256) v = S1[(size_t)(k - 256) * N + n];
    else                v = S0[(size_t)k * N + n];
    ws[i] = (__bf16)v;
}

// ============ fused kernel: MT=64, 512 threads, 76KB LDS -> 2 blocks/CU (16 waves) ============
// r13 had LDS=80KB -> 2x80=160KB exactly = full pool -> 2nd block never co-resided
// (occupancy 21%). SY shrunk to its used 12288B -> 77824B/block -> 2 blocks truly fit.
extern "C" __global__ void __launch_bounds__(512, 2)
fused_ext_attn(const float* __restrict__ query, const float* __restrict__ key,
               const float* __restrict__ value, const float* __restrict__ refp,
               const float* __restrict__ pose,
               const __bf16* __restrict__ ws,
               const float* __restrict__ bq, const float* __restrict__ bk,
               const float* __restrict__ bv, const float* __restrict__ bpos,
               const float* __restrict__ bo1, const float* __restrict__ bo2,
               const float* __restrict__ bout,
               float* __restrict__ out)
{
    const __bf16* WTqp  = ws;             // KC=16
    const __bf16* WTkp  = ws + 131072;    // KC=16
    const __bf16* WTo1  = ws + 262144;    // KC=8
    const __bf16* WTo2  = ws + 393216;    // KC=16
    const __bf16* WTv   = ws + 425984;    // KC=8
    const __bf16* WTout = ws + 491520;    // KC=8

    __shared__ __attribute__((aligned(16))) __bf16 SA[MT * CC];   // query -> key -> value
    __shared__ __attribute__((aligned(16))) __bf16 SX[MT * CC];   // h1 -> pose -> o
    __shared__ __attribute__((aligned(16))) char   SY[12288];     // off(bf16,8K) qk(2K) wv(2K)

    __bf16* off_b = (__bf16*)SY;          // [64][64] bf16
    float*  qk_s  = (float*)(SY + 8192);  // [64][8]
    float*  wv_s  = (float*)(SY + 10240); // [64][8]

    const int tid = threadIdx.x;
    const int lane = tid & 63;
    const int wid = tid >> 6;        // 0..7 — this wave's head (q/k/v/out phases: cols 32w..32w+32)
    const int r16 = lane & 15;
    const int q4 = lane >> 4;
    const int laneoff = lane * 8;
    const int row0 = blockIdx.x * MT;

    // ---- P1: stage query -> SA ----
    stream_tile(query, row0, tid, SA);
    __syncthreads();                                   // B1

    // ---- P2..P5: h1 (2x256-col passes) + off (waves 0-3, accumulate in regs) ----
    f32x4 accO[4];
#pragma unroll
    for (int i = 0; i < 4; ++i) accO[i] = (f32x4){0.f, 0.f, 0.f, 0.f};
    for (int p = 0; p < 2; ++p) {
        f32x4 acc[4][2];
#pragma unroll
        for (int i = 0; i < 4; ++i)
#pragma unroll
            for (int j = 0; j < 2; ++j) acc[i][j] = (f32x4){0.f, 0.f, 0.f, 0.f};
#pragma unroll
        for (int ks = 0; ks < 8; ++ks) {
            int ak = ks * 32 + q4 * 8;
            bf16x8 a[4], b[2];
#pragma unroll
            for (int mf = 0; mf < 4; ++mf)
                a[mf] = *(const bf16x8*)((const char*)SA + swz(mf * 16 + r16, ak));
#pragma unroll
            for (int nf = 0; nf < 2; ++nf)
                b[nf] = ldB(WTo1, p * 16 + wid * 2 + nf, 8, ks, laneoff);
#pragma unroll
            for (int mf = 0; mf < 4; ++mf)
#pragma unroll
                for (int nf = 0; nf < 2; ++nf)
                    acc[mf][nf] = __builtin_amdgcn_mfma_f32_16x16x32_bf16(a[mf], b[nf], acc[mf][nf], 0, 0, 0);
        }
#pragma unroll
        for (int mf = 0; mf < 4; ++mf)
#pragma unroll
            for (int nf = 0; nf < 2; ++nf) {
                int col = wid * 32 + nf * 16 + r16;
                float bias = bo1[p * 256 + col];
#pragma unroll
                for (int r = 0; r < 4; ++r)
                    *(__bf16*)((char*)SX + swz(mf * 16 + q4 * 4 + r, col)) =
                        (__bf16)fmaxf(acc[mf][nf][r] + bias, 0.f);
            }
        __syncthreads();                               // B2 / B4
        if (wid < 4) {
#pragma unroll
            for (int ks = 0; ks < 8; ++ks) {
                int ak = ks * 32 + q4 * 8;
                bf16x8 b = ldB(WTo2, wid, 16, p * 8 + ks, laneoff);
#pragma unroll
                for (int mf = 0; mf < 4; ++mf) {
                    bf16x8 a = *(const bf16x8*)((const char*)SX + swz(mf * 16 + r16, ak));
                    accO[mf] = __builtin_amdgcn_mfma_f32_16x16x32_bf16(a, b, accO[mf], 0, 0, 0);
                }
            }
            if (p == 1) {
                int col = wid * 16 + r16;
                float b2 = bo2[col];
#pragma unroll
                for (int mf = 0; mf < 4; ++mf)
#pragma unroll
                    for (int r = 0; r < 4; ++r)
                        off_b[(mf * 16 + q4 * 4 + r) * 64 + col] = (__bf16)(accO[mf][r] + b2);
            }
        }
        __syncthreads();                               // B3 / B5
    }

    // ---- P6: stage pose -> SX ; q-GEMM part1 (A = query in SA) ----
    f32x4 qa[4][2];
#pragma unroll
    for (int i = 0; i < 4; ++i)
#pragma unroll
        for (int j = 0; j < 2; ++j) qa[i][j] = (f32x4){0.f, 0.f, 0.f, 0.f};
    stream_tile(pose, row0, tid, SX);
#pragma unroll
    for (int ks = 0; ks < 8; ++ks) {
        int ak = ks * 32 + q4 * 8;
        bf16x8 a[4], b[2];
#pragma unroll
        for (int mf = 0; mf < 4; ++mf)
            a[mf] = *(const bf16x8*)((const char*)SA + swz(mf * 16 + r16, ak));
#pragma unroll
        for (int nf = 0; nf < 2; ++nf)
            b[nf] = ldB(WTqp, wid * 2 + nf, 16, ks, laneoff);
#pragma unroll
        for (int mf = 0; mf < 4; ++mf)
#pragma unroll
            for (int nf = 0; nf < 2; ++nf)
                qa[mf][nf] = __builtin_amdgcn_mfma_f32_16x16x32_bf16(a[mf], b[nf], qa[mf][nf], 0, 0, 0);
    }
    __syncthreads();                                   // B6

    // ---- P7: stage key -> SA ; q-GEMM part2 (A = pose in SX) ----
    stream_tile(key, row0, tid, SA);
#pragma unroll
    for (int ks = 8; ks < 16; ++ks) {
        int ak = (ks - 8) * 32 + q4 * 8;
        bf16x8 a[4], b[2];
#pragma unroll
        for (int mf = 0; mf < 4; ++mf)
            a[mf] = *(const bf16x8*)((const char*)SX + swz(mf * 16 + r16, ak));
#pragma unroll
        for (int nf = 0; nf < 2; ++nf)
            b[nf] = ldB(WTqp, wid * 2 + nf, 16, ks, laneoff);
#pragma unroll
        for (int mf = 0; mf < 4; ++mf)
#pragma unroll
            for (int nf = 0; nf < 2; ++nf)
                qa[mf][nf] = __builtin_amdgcn_mfma_f32_16x16x32_bf16(a[mf], b[nf], qa[mf][nf], 0, 0, 0);
    }
    __syncthreads();                                   // B7

    // ---- P8: k-GEMM (K=512: key in SA, pose in SX) ; head dot -> qk_s ----
    {
        f32x4 ka[4][2];
#pragma unroll
        for (int i = 0; i < 4; ++i)
#pragma unroll
            for (int j = 0; j < 2; ++j) ka[i][j] = (f32x4){0.f, 0.f, 0.f, 0.f};
#pragma unroll
        for (int ks = 0; ks < 16; ++ks) {
            int ak = (ks & 7) * 32 + q4 * 8;
            const char* Abase = (ks < 8) ? (const char*)SA : (const char*)SX;
            bf16x8 a[4], b[2];
#pragma unroll
            for (int mf = 0; mf < 4; ++mf)
                a[mf] = *(const bf16x8*)(Abase + swz(mf * 16 + r16, ak));
#pragma unroll
            for (int nf = 0; nf < 2; ++nf)
                b[nf] = ldB(WTkp, wid * 2 + nf, 16, ks, laneoff);
#pragma unroll
            for (int mf = 0; mf < 4; ++mf)
#pragma unroll
                for (int nf = 0; nf < 2; ++nf)
                    ka[mf][nf] = __builtin_amdgcn_mfma_f32_16x16x32_bf16(a[mf], b[nf], ka[mf][nf], 0, 0, 0);
        }
        float Bq[2], Bk[2];
#pragma unroll
        for (int nf = 0; nf < 2; ++nf) {
            int col = wid * 32 + nf * 16 + r16;
            Bq[nf] = bq[col] + bpos[col];
            Bk[nf] = bk[col] + bpos[col];
        }
#pragma unroll
        for (int mf = 0; mf < 4; ++mf)
#pragma unroll
            for (int r = 0; r < 4; ++r) {
                float p0 = (qa[mf][0][r] + Bq[0]) * (ka[mf][0][r] + Bk[0])
                         + (qa[mf][1][r] + Bq[1]) * (ka[mf][1][r] + Bk[1]);
#pragma unroll
                for (int m = 1; m < 16; m <<= 1)
                    p0 += __shfl_xor(p0, m);
                if (r16 == 0)
                    qk_s[(mf * 16 + q4 * 4 + r) * 8 + wid] = p0;
            }
    }
    __syncthreads();                                   // B8

    // ---- P9: stage value -> SA ; softmax (512 jobs: t=tid>>3, h=tid&7) -> wv_s ----
    stream_tile(value, row0, tid, SA);
    {
        int t = tid >> 3, h = tid & 7;
        float qk = qk_s[t * 8 + h];
        f32x2 rp = __builtin_nontemporal_load((const f32x2*)(refp + (size_t)(row0 + t) * 2));
        float wgt[4], lg[4];
        float m = -1e30f;
#pragma unroll
        for (int kk = 0; kk < 4; ++kk) {
            float ox = (float)off_b[t * 64 + (h * 4 + kk) * 2];
            float oy = (float)off_b[t * 64 + (h * 4 + kk) * 2 + 1];
            float cx = rp[0] + ox - 0.5f, cy = rp[1] + oy - 0.5f;
            float wx = fmaxf(0.f, 1.f - fabsf(cx));
            float wy = fmaxf(0.f, 1.f - fabsf(cy));
            wgt[kk] = wx * wy;
            lg[kk] = qk * wgt[kk] * 0.17677669529663687f;  // 1/sqrt(32)
            m = fmaxf(m, lg[kk]);
        }
        float s = 0.f, sw = 0.f;
#pragma unroll
        for (int kk = 0; kk < 4; ++kk) {
            float e = __expf(lg[kk] - m);
            s += e;
            sw += e * wgt[kk];
        }
        wv_s[t * 8 + h] = sw / s;
    }
    __syncthreads();                                   // B9

    // ---- P10: o = (value@Wv + bv) * wv -> SX ----
    {
        f32x4 acc[4][2];
#pragma unroll
        for (int i = 0; i < 4; ++i)
#pragma unroll
            for (int j = 0; j < 2; ++j) acc[i][j] = (f32x4){0.f, 0.f, 0.f, 0.f};
#pragma unroll
        for (int ks = 0; ks < 8; ++ks) {
            int ak = ks * 32 + q4 * 8;
            bf16x8 a[4], b[2];
#pragma unroll
            for (int mf = 0; mf < 4; ++mf)
                a[mf] = *(const bf16x8*)((const char*)SA + swz(mf * 16 + r16, ak));
#pragma unroll
            for (int nf = 0; nf < 2; ++nf)
                b[nf] = ldB(WTv, wid * 2 + nf, 8, ks, laneoff);
#pragma unroll
            for (int mf = 0; mf < 4; ++mf)
#pragma unroll
                for (int nf = 0; nf < 2; ++nf)
                    acc[mf][nf] = __builtin_amdgcn_mfma_f32_16x16x32_bf16(a[mf], b[nf], acc[mf][nf], 0, 0, 0);
        }
#pragma unroll
        for (int mf = 0; mf < 4; ++mf)
#pragma unroll
            for (int nf = 0; nf < 2; ++nf) {
                int col = wid * 32 + nf * 16 + r16;   // head = wid
                float bias = bv[col];
#pragma unroll
                for (int r = 0; r < 4; ++r) {
                    int row = mf * 16 + q4 * 4 + r;
                    float wvv = wv_s[row * 8 + wid];
                    *(__bf16*)((char*)SX + swz(row, col)) = (__bf16)((acc[mf][nf][r] + bias) * wvv);
                }
            }
    }
    __syncthreads();                                   // B10

    // ---- P11: out = o @ WTout + bout -> global (NT store) ----
    {
        f32x4 acc[4][2];
#pragma unroll
        for (int i = 0; i < 4; ++i)
#pragma unroll
            for (int j = 0; j < 2; ++j) acc[i][j] = (f32x4){0.f, 0.f, 0.f, 0.f};
#pragma unroll
        for (int ks = 0; ks < 8; ++ks) {
            int ak = ks * 32 + q4 * 8;
            bf16x8 a[4], b[2];
#pragma unroll
            for (int mf = 0; mf < 4; ++mf)
                a[mf] = *(const bf16x8*)((const char*)SX + swz(mf * 16 + r16, ak));
#pragma unroll
            for (int nf = 0; nf < 2; ++nf)
                b[nf] = ldB(WTout, wid * 2 + nf, 8, ks, laneoff);
#pragma unroll
            for (int mf = 0; mf < 4; ++mf)
#pragma unroll
                for (int nf = 0; nf < 2; ++nf)
                    acc[mf][nf] = __builtin_amdgcn_mfma_f32_16x16x32_bf16(a[mf], b[nf], acc[mf][nf], 0, 0, 0);
        }
#pragma unroll
        for (int mf = 0; mf < 4; ++mf)
#pragma unroll
            for (int nf = 0; nf < 2; ++nf) {
                int col = wid * 32 + nf * 16 + r16;
                float bias = bout[col];
#pragma unroll
                for (int r = 0; r < 4; ++r) {
                    int row = mf * 16 + q4 * 4 + r;
                    __builtin_nontemporal_store(acc[mf][nf][r] + bias,
                                                out + (size_t)(row0 + row) * CC + col);
                }
            }
    }
}

extern "C" void kernel_launch(void* const* d_in, const int* in_sizes, int n_in,
                              void* d_out, int out_size, void* d_ws, size_t ws_size,
                              hipStream_t stream)
{
    const float* query = (const float*)d_in[0];
    const float* key   = (const float*)d_in[1];
    const float* value = (const float*)d_in[2];
    const float* refp  = (const float*)d_in[3];
    const float* pose  = (const float*)d_in[4];
    const float* Wq  = (const float*)d_in[5];  const float* bq   = (const float*)d_in[6];
    const float* Wk  = (const float*)d_in[7];  const float* bk   = (const float*)d_in[8];
    const float* Wv  = (const float*)d_in[9];  const float* bv   = (const float*)d_in[10];
    const float* Wo1 = (const float*)d_in[11]; const float* bo1  = (const float*)d_in[12];
    const float* Wo2 = (const float*)d_in[13]; const float* bo2  = (const float*)d_in[14];
    const float* Wpos= (const float*)d_in[15]; const float* bpos = (const float*)d_in[16];
    const float* Wout= (const float*)d_in[17]; const float* bout = (const float*)d_in[18];

    __bf16* ws = (__bf16*)d_ws;

    prep_all<<<2176, 256, 0, stream>>>(Wq, Wk, Wpos, Wo1, Wo2, Wv, Wout, ws);

    fused_ext_attn<<<65536 / MT, 512, 0, stream>>>(
        query, key, value, refp, pose, ws,
        bq, bk, bv, bpos, bo1, bo2, bout, (float*)d_out);
}